// Round 4
// baseline (38738.193 us; speedup 1.0000x reference)
//
#include <hip/hip_runtime.h>
#include <hip/hip_fp16.h>
#include <math.h>

#define Hn 1024
#define Bn 4096
#define INW 33
#define OUTS (Bn * Hn)
#define TPB 512

typedef _Float16 half2v __attribute__((ext_vector_type(2)));
typedef unsigned uint4v __attribute__((ext_vector_type(4)));

__device__ __forceinline__ float sigmoidf_(float x) {
    return 1.0f / (1.0f + __expf(-x));
}
__device__ __forceinline__ float tanhf_(float x) {
    float e = __expf(-2.0f * fabsf(x));
    float r = (1.0f - e) / (1.0f + e);
    return copysignf(r, x);
}
__device__ __forceinline__ unsigned pack2(float a, float b) {
    __half2 h = __floats2half2_rn(a, b);
    return __builtin_bit_cast(unsigned, h);
}
__device__ __forceinline__ float dot2acc(unsigned w, unsigned hv, float acc) {
#if __has_builtin(__builtin_amdgcn_fdot2)
    return __builtin_amdgcn_fdot2(__builtin_bit_cast(half2v, w),
                                  __builtin_bit_cast(half2v, hv), acc, false);
#else
    __half2 wh = __builtin_bit_cast(__half2, w);
    __half2 hh = __builtin_bit_cast(__half2, hv);
    float2 wf = __half22float2(wh), hf = __half22float2(hh);
    return acc + wf.x * hf.x + wf.y * hf.y;
#endif
}

// Flag byte for step-tag v (v = t or t+1). Avoid the 0xAA ws-poison value.
__device__ __forceinline__ unsigned char tagb_of(unsigned v) {
    unsigned char b = (unsigned char)v;
    return (b == 0xAAu) ? (unsigned char)(b ^ 0xFFu) : b;
}

// Cheap detection spin: read nwords u64 flag words (8 flag bytes each) with
// device-coherent loads. 4-8 line-requests per wave per round vs 64 for the
// full data row — this is the steady-state poll traffic now.
__device__ __forceinline__ void spin_flags(const unsigned long long* frow, int lane,
                                           int nwords, unsigned char tb) {
    unsigned long long want = 0x0101010101010101ULL * (unsigned long long)tb;
    int rounds = 0;
    for (;;) {
        bool ok = true;
        if (lane < nwords) {
            unsigned long long v;
            asm volatile("global_load_dwordx2 %0, %1, off sc0 sc1\n\t"
                         "s_waitcnt vmcnt(0)"
                         : "=v"(v) : "v"(frow + lane) : "memory");
            ok = (v == want);
        }
        if (__all(ok)) break;
        if (++rounds > (1 << 24)) break;  // bailout: wrong answer beats a wedged GPU
    }
}

// One-shot (usually) read of a 512-packet row (4 KB), tag-verified; loops only
// if flag stores raced ahead of data stores (rare). Lane i owns 16 B at
// row + 16*i per 1 KB stripe. sc0 sc1 = device-coherent, reads LLC.
__device__ __forceinline__ void poll_row(const unsigned long long* rowbase, int lane,
                                         unsigned tag, uint4v& r0, uint4v& r1,
                                         uint4v& r2, uint4v& r3) {
    const char* p = (const char*)rowbase + lane * 16;
    int rounds = 0;
    for (;;) {
        asm volatile(
            "global_load_dwordx4 %0, %4, off sc0 sc1\n\t"
            "global_load_dwordx4 %1, %4, off offset:1024 sc0 sc1\n\t"
            "global_load_dwordx4 %2, %4, off offset:2048 sc0 sc1\n\t"
            "global_load_dwordx4 %3, %4, off offset:3072 sc0 sc1\n\t"
            "s_waitcnt vmcnt(0)"
            : "=v"(r0), "=v"(r1), "=v"(r2), "=v"(r3)
            : "v"(p)
            : "memory");
        bool ok = (r0.y == tag) & (r0.w == tag) & (r1.y == tag) & (r1.w == tag)
                & (r2.y == tag) & (r2.w == tag) & (r3.y == tag) & (r3.w == tag);
        if (__all(ok)) break;
        if (++rounds > (1 << 22)) break;  // bailout
    }
}

// deposit a polled row into LDS at hs2[base .. base+511]
__device__ __forceinline__ void row_to_lds(unsigned* hs2, int base, int lane,
                                           const uint4v& r0, const uint4v& r1,
                                           const uint4v& r2, const uint4v& r3) {
    hs2[base +       2 * lane]     = r0.x;  hs2[base +       2 * lane + 1] = r0.z;
    hs2[base + 128 + 2 * lane]     = r1.x;  hs2[base + 128 + 2 * lane + 1] = r1.z;
    hs2[base + 256 + 2 * lane]     = r2.x;  hs2[base + 256 + 2 * lane + 1] = r2.z;
    hs2[base + 384 + 2 * lane]     = r3.x;  hs2[base + 384 + 2 * lane + 1] = r3.z;
}

// xin = [x | ip_emb[ip] | port_emb[port]]  (4096 x 33)
__global__ void prep_kernel(const float* __restrict__ x, const int* __restrict__ ip,
                            const int* __restrict__ port, const float* __restrict__ ip_emb,
                            const float* __restrict__ port_emb, float* __restrict__ xin) {
    int gid = blockIdx.x * blockDim.x + threadIdx.x;
    if (gid < Bn * INW) {
        int t = gid / INW;
        int k = gid - t * INW;
        float v;
        if (k < 17) {
            v = x[t * 17 + k];
        } else if (k < 25) {
            v = ip_emb[ip[t * 8 + (k - 17)]];
        } else {
            int kk = k - 25;
            v = port_emb[port[t * 2 + (kk >> 2)] * 4 + (kk & 3)];
        }
        xin[gid] = v;
    }
}

__global__ void __launch_bounds__(TPB, 2) lstm_kernel(
    const float* __restrict__ xin,
    const float* __restrict__ hid0, const float* __restrict__ cel0,
    const float* __restrict__ Wih0, const float* __restrict__ Whh0,
    const float* __restrict__ bih0, const float* __restrict__ bhh0,
    const float* __restrict__ Wih1, const float* __restrict__ Whh1,
    const float* __restrict__ bih1, const float* __restrict__ bhh1,
    float* __restrict__ out,
    unsigned long long* __restrict__ h0pkt,   // [4096][512] : tag|h0 pair
    unsigned long long* __restrict__ h1pkt,   // [4096][512] : tag|h1 pair
    unsigned char* __restrict__ f0flag,       // [4096][256] : per-L0-wave flag
    unsigned char* __restrict__ f1flag)       // [4096][512] : per-L1-wave flag
{
    __shared__ unsigned hs2[1024];   // half2 chunks of the input vector(s)
    const int tid  = threadIdx.x;
    const int lane = tid & 63;
    const int wave = tid >> 6;
    const int bx   = blockIdx.x;

    if (bx < 32) {
        // ================= layer 0 : 32 blocks, wave owns 4 h-indices ========
        const int j0  = bx * 32 + wave * 4;
        const int fid = bx * 8 + wave;          // this wave's flag byte index
        unsigned w2[4][4][8];     // f16-pair weights of Whh0
        float    wx[4][4];        // fp32 x-weights (lane < 33)
        float    bs[4][4];
#pragma unroll
        for (int jj = 0; jj < 4; ++jj) {
#pragma unroll
            for (int g = 0; g < 4; ++g) {
                const int row = g * Hn + (j0 + jj);
                const float* wr = Whh0 + (size_t)row * Hn;
#pragma unroll
                for (int k = 0; k < 8; ++k) {
                    int c = lane + 64 * k;
                    w2[jj][g][k] = pack2(wr[2 * c], wr[2 * c + 1]);
                }
                wx[jj][g] = (lane < INW) ? Wih0[row * INW + lane] : 0.0f;
                bs[jj][g] = bih0[row] + bhh0[row];
            }
        }
        float cst[4], hcur[4];
#pragma unroll
        for (int jj = 0; jj < 4; ++jj) { cst[jj] = cel0[j0 + jj]; hcur[jj] = 0.0f; }

        for (int t = 0; t < Bn; ++t) {
            float xv = xin[t * INW + (lane < INW ? lane : 0)];  // prefetch
            if (wave == 0) {
                if (t == 0) {
#pragma unroll
                    for (int m = 0; m < 8; ++m) {
                        int q = lane + 64 * m;
                        hs2[q] = pack2(hid0[2 * q], hid0[2 * q + 1]);
                    }
                } else {
                    spin_flags((const unsigned long long*)(f0flag + (size_t)(t - 1) * 256),
                               lane, 32, tagb_of((unsigned)t));
                    uint4v r0, r1, r2, r3;
                    poll_row(h0pkt + (size_t)(t - 1) * 512, lane, (unsigned)t, r0, r1, r2, r3);
                    row_to_lds(hs2, 0, lane, r0, r1, r2, r3);
                }
            }
            __syncthreads();

            float acc[4][4];
#pragma unroll
            for (int jj = 0; jj < 4; ++jj)
#pragma unroll
                for (int g = 0; g < 4; ++g) acc[jj][g] = wx[jj][g] * xv;
#pragma unroll
            for (int k = 0; k < 8; ++k) {
                unsigned hv = hs2[lane + 64 * k];   // 2-way bank alias: free
#pragma unroll
                for (int jj = 0; jj < 4; ++jj)
#pragma unroll
                    for (int g = 0; g < 4; ++g)
                        acc[jj][g] = dot2acc(w2[jj][g][k], hv, acc[jj][g]);
            }
            __syncthreads();   // hs2 reads done; next iter may overwrite

#pragma unroll
            for (int off = 32; off >= 1; off >>= 1)
#pragma unroll
                for (int jj = 0; jj < 4; ++jj)
#pragma unroll
                    for (int g = 0; g < 4; ++g)
                        acc[jj][g] += __shfl_xor(acc[jj][g], off);

#pragma unroll
            for (int jj = 0; jj < 4; ++jj) {
                float gi = sigmoidf_(acc[jj][0] + bs[jj][0]);
                float gf = sigmoidf_(acc[jj][1] + bs[jj][1]);
                float gg = tanhf_   (acc[jj][2] + bs[jj][2]);
                float go = sigmoidf_(acc[jj][3] + bs[jj][3]);
                cst[jj] = gf * cst[jj] + gi * gg;
                hcur[jj] = go * tanhf_(cst[jj]);
            }
            if (lane == 0) {
                unsigned long long tw = ((unsigned long long)(t + 1)) << 32;
                __hip_atomic_store(&h0pkt[(size_t)t * 512 + (j0 >> 1)],
                                   tw | pack2(hcur[0], hcur[1]),
                                   __ATOMIC_RELAXED, __HIP_MEMORY_SCOPE_AGENT);
                __hip_atomic_store(&h0pkt[(size_t)t * 512 + (j0 >> 1) + 1],
                                   tw | pack2(hcur[2], hcur[3]),
                                   __ATOMIC_RELAXED, __HIP_MEMORY_SCOPE_AGENT);
                // detection flag: fire-and-forget; tag-verify covers reordering
                __hip_atomic_store(f0flag + (size_t)t * 256 + fid,
                                   tagb_of((unsigned)(t + 1)),
                                   __ATOMIC_RELAXED, __HIP_MEMORY_SCOPE_AGENT);
            }
        }
        if (lane == 0) {
#pragma unroll
            for (int jj = 0; jj < 4; ++jj) {
                out[OUTS + j0 + jj] = hcur[jj];            // hf layer 0
                out[OUTS + 2 * Hn + j0 + jj] = cst[jj];    // cf layer 0
            }
        }
    } else {
        // ================= layer 1 : 64 blocks, wave owns 2 h-indices ========
        const int blk = bx - 32;
        const int j0  = blk * 16 + wave * 2;
        const int fid = blk * 8 + wave;
        unsigned w2[2][4][16];    // k<8: Wih1 (vs h0[t]) ; k>=8: Whh1 (vs h1[t-1])
        float    bs[2][4];
#pragma unroll
        for (int jj = 0; jj < 2; ++jj) {
#pragma unroll
            for (int g = 0; g < 4; ++g) {
                const int row = g * Hn + (j0 + jj);
                const float* wr1 = Wih1 + (size_t)row * Hn;
                const float* wr2 = Whh1 + (size_t)row * Hn;
#pragma unroll
                for (int k = 0; k < 8; ++k) {
                    int c = lane + 64 * k;
                    w2[jj][g][k]     = pack2(wr1[2 * c], wr1[2 * c + 1]);
                    w2[jj][g][8 + k] = pack2(wr2[2 * c], wr2[2 * c + 1]);
                }
                bs[jj][g] = bih1[row] + bhh1[row];
            }
        }
        float cst[2], hcur[2];
#pragma unroll
        for (int jj = 0; jj < 2; ++jj) { cst[jj] = cel0[Hn + j0 + jj]; hcur[jj] = 0.0f; }

        for (int t = 0; t < Bn; ++t) {
            if (wave == 0) {
                spin_flags((const unsigned long long*)(f0flag + (size_t)t * 256),
                           lane, 32, tagb_of((unsigned)(t + 1)));
                uint4v r0, r1, r2, r3;
                poll_row(h0pkt + (size_t)t * 512, lane, (unsigned)(t + 1), r0, r1, r2, r3);
                row_to_lds(hs2, 0, lane, r0, r1, r2, r3);          // h0[t]
            } else if (wave == 1) {
                if (t == 0) {
#pragma unroll
                    for (int m = 0; m < 8; ++m) {
                        int q = lane + 64 * m;
                        hs2[512 + q] = pack2(hid0[Hn + 2 * q], hid0[Hn + 2 * q + 1]);
                    }
                } else {
                    spin_flags((const unsigned long long*)(f1flag + (size_t)(t - 1) * 512),
                               lane, 64, tagb_of((unsigned)t));
                    uint4v r0, r1, r2, r3;
                    poll_row(h1pkt + (size_t)(t - 1) * 512, lane, (unsigned)t, r0, r1, r2, r3);
                    row_to_lds(hs2, 512, lane, r0, r1, r2, r3);    // h1[t-1]
                }
            }
            __syncthreads();

            float acc[2][4];
#pragma unroll
            for (int jj = 0; jj < 2; ++jj)
#pragma unroll
                for (int g = 0; g < 4; ++g) acc[jj][g] = 0.0f;
#pragma unroll
            for (int k = 0; k < 16; ++k) {
                unsigned hv = hs2[lane + 64 * k];
#pragma unroll
                for (int jj = 0; jj < 2; ++jj)
#pragma unroll
                    for (int g = 0; g < 4; ++g)
                        acc[jj][g] = dot2acc(w2[jj][g][k], hv, acc[jj][g]);
            }
            __syncthreads();

#pragma unroll
            for (int off = 32; off >= 1; off >>= 1)
#pragma unroll
                for (int jj = 0; jj < 2; ++jj)
#pragma unroll
                    for (int g = 0; g < 4; ++g)
                        acc[jj][g] += __shfl_xor(acc[jj][g], off);

#pragma unroll
            for (int jj = 0; jj < 2; ++jj) {
                float gi = sigmoidf_(acc[jj][0] + bs[jj][0]);
                float gf = sigmoidf_(acc[jj][1] + bs[jj][1]);
                float gg = tanhf_   (acc[jj][2] + bs[jj][2]);
                float go = sigmoidf_(acc[jj][3] + bs[jj][3]);
                cst[jj] = gf * cst[jj] + gi * gg;
                hcur[jj] = go * tanhf_(cst[jj]);
            }
            if (lane == 0) {
                unsigned long long tw = ((unsigned long long)(t + 1)) << 32;
                __hip_atomic_store(&h1pkt[(size_t)t * 512 + (j0 >> 1)],
                                   tw | pack2(hcur[0], hcur[1]),
                                   __ATOMIC_RELAXED, __HIP_MEMORY_SCOPE_AGENT);
                __hip_atomic_store(f1flag + (size_t)t * 512 + fid,
                                   tagb_of((unsigned)(t + 1)),
                                   __ATOMIC_RELAXED, __HIP_MEMORY_SCOPE_AGENT);
                float2 o2 = make_float2(fmaxf(hcur[0], 0.0f), fmaxf(hcur[1], 0.0f));
                *(float2*)(out + (size_t)t * Hn + j0) = o2;   // outputs[t] = relu(h1)
            }
        }
        if (lane == 0) {
#pragma unroll
            for (int jj = 0; jj < 2; ++jj) {
                out[OUTS + Hn + j0 + jj] = hcur[jj];           // hf layer 1
                out[OUTS + 3 * Hn + j0 + jj] = cst[jj];        // cf layer 1
            }
        }
    }
}

extern "C" void kernel_launch(void* const* d_in, const int* in_sizes, int n_in,
                              void* d_out, int out_size, void* d_ws, size_t ws_size,
                              hipStream_t stream) {
    const float* x        = (const float*)d_in[0];
    const int*   ip       = (const int*)d_in[1];
    const int*   port     = (const int*)d_in[2];
    const float* hidden   = (const float*)d_in[3];
    const float* cell     = (const float*)d_in[4];
    const float* ip_emb   = (const float*)d_in[5];
    const float* port_emb = (const float*)d_in[6];
    const float* Wih0     = (const float*)d_in[7];
    const float* Whh0     = (const float*)d_in[8];
    const float* bih0     = (const float*)d_in[9];
    const float* bhh0     = (const float*)d_in[10];
    const float* Wih1     = (const float*)d_in[11];
    const float* Whh1     = (const float*)d_in[12];
    const float* bih1     = (const float*)d_in[13];
    const float* bhh1     = (const float*)d_in[14];
    float* out = (float*)d_out;

    // ws layout: h0pkt | h1pkt (u64 [4096][512] each) | f0flag [4096][256] |
    //            f1flag [4096][512] | xin (4096x33 f32)  ~= 37 MB.
    // Tags/flags never match the 0xAA poison, so no zeroing pass is needed.
    unsigned long long* h0pkt = (unsigned long long*)d_ws;
    unsigned long long* h1pkt = h0pkt + (size_t)Bn * 512;
    unsigned char* f0flag = (unsigned char*)(h1pkt + (size_t)Bn * 512);
    unsigned char* f1flag = f0flag + (size_t)Bn * 256;
    float* xin = (float*)(f1flag + (size_t)Bn * 512);

    prep_kernel<<<dim3((Bn * INW + 255) / 256), dim3(256), 0, stream>>>(
        x, ip, port, ip_emb, port_emb, xin);

    lstm_kernel<<<dim3(96), dim3(TPB), 0, stream>>>(
        xin, hidden, cell, Wih0, Whh0, bih0, bhh0, Wih1, Whh1, bih1, bhh1,
        out, h0pkt, h1pkt, f0flag, f1flag);
}

// Round 5
// 17659.187 us; speedup vs baseline: 2.1937x; 2.1937x over previous
//
#include <hip/hip_runtime.h>
#include <hip/hip_fp16.h>
#include <math.h>

#define Hn 1024
#define Bn 4096
#define INW 33
#define OUTS (Bn * Hn)
#define TPB 512

typedef _Float16 half2v __attribute__((ext_vector_type(2)));
typedef unsigned uint4v __attribute__((ext_vector_type(4)));

__device__ __forceinline__ float sigmoidf_(float x) {
    return 1.0f / (1.0f + __expf(-x));
}
__device__ __forceinline__ float tanhf_(float x) {
    float e = __expf(-2.0f * fabsf(x));
    float r = (1.0f - e) / (1.0f + e);
    return copysignf(r, x);
}
__device__ __forceinline__ unsigned pack2(float a, float b) {
    __half2 h = __floats2half2_rn(a, b);
    return __builtin_bit_cast(unsigned, h);
}
__device__ __forceinline__ float dot2acc(unsigned w, unsigned hv, float acc) {
#if __has_builtin(__builtin_amdgcn_fdot2)
    return __builtin_amdgcn_fdot2(__builtin_bit_cast(half2v, w),
                                  __builtin_bit_cast(half2v, hv), acc, false);
#else
    __half2 wh = __builtin_bit_cast(__half2, w);
    __half2 hh = __builtin_bit_cast(__half2, hv);
    float2 wf = __half22float2(wh), hf = __half22float2(hh);
    return acc + wf.x * hf.x + wf.y * hf.y;
#endif
}

// Single-phase poll of one 512-packet row (4 KB), data-is-the-flag.
// Lane i owns 16 B at row + 16*i per 1 KB stripe; sc0 sc1 = device-coherent.
// Backoff only after repeated failures: thins the read storm exactly when a
// producer store needs the line (writer-starvation mitigation).
__device__ __forceinline__ void poll_row(const unsigned long long* rowbase, int lane,
                                         unsigned tag, uint4v& r0, uint4v& r1,
                                         uint4v& r2, uint4v& r3) {
    const char* p = (const char*)rowbase + lane * 16;
    int rounds = 0;
    for (;;) {
        asm volatile(
            "global_load_dwordx4 %0, %4, off sc0 sc1\n\t"
            "global_load_dwordx4 %1, %4, off offset:1024 sc0 sc1\n\t"
            "global_load_dwordx4 %2, %4, off offset:2048 sc0 sc1\n\t"
            "global_load_dwordx4 %3, %4, off offset:3072 sc0 sc1\n\t"
            "s_waitcnt vmcnt(0)"
            : "=v"(r0), "=v"(r1), "=v"(r2), "=v"(r3)
            : "v"(p)
            : "memory");
        bool ok = (r0.y == tag) & (r0.w == tag) & (r1.y == tag) & (r1.w == tag)
                & (r2.y == tag) & (r2.w == tag) & (r3.y == tag) & (r3.w == tag);
        if (__all(ok)) break;
        if (++rounds > (1 << 22)) break;  // bailout: wrong answer beats a wedged GPU
        if (rounds > 2) __builtin_amdgcn_s_sleep(2);   // ~128 cy backoff while truly waiting
    }
}

// deposit a polled row into LDS at hs2[base .. base+511]
__device__ __forceinline__ void row_to_lds(unsigned* hs2, int base, int lane,
                                           const uint4v& r0, const uint4v& r1,
                                           const uint4v& r2, const uint4v& r3) {
    hs2[base +       2 * lane]     = r0.x;  hs2[base +       2 * lane + 1] = r0.z;
    hs2[base + 128 + 2 * lane]     = r1.x;  hs2[base + 128 + 2 * lane + 1] = r1.z;
    hs2[base + 256 + 2 * lane]     = r2.x;  hs2[base + 256 + 2 * lane + 1] = r2.z;
    hs2[base + 384 + 2 * lane]     = r3.x;  hs2[base + 384 + 2 * lane + 1] = r3.z;
}

__device__ __forceinline__ void store16_coherent(void* dst, uint4v v) {
    asm volatile("global_store_dwordx4 %0, %1, off sc0 sc1"
                 :: "v"(dst), "v"(v) : "memory");
}

// xin = [x | ip_emb[ip] | port_emb[port]]  (4096 x 33)
__global__ void prep_kernel(const float* __restrict__ x, const int* __restrict__ ip,
                            const int* __restrict__ port, const float* __restrict__ ip_emb,
                            const float* __restrict__ port_emb, float* __restrict__ xin) {
    int gid = blockIdx.x * blockDim.x + threadIdx.x;
    if (gid < Bn * INW) {
        int t = gid / INW;
        int k = gid - t * INW;
        float v;
        if (k < 17) {
            v = x[t * 17 + k];
        } else if (k < 25) {
            v = ip_emb[ip[t * 8 + (k - 17)]];
        } else {
            int kk = k - 25;
            v = port_emb[port[t * 2 + (kk >> 2)] * 4 + (kk & 3)];
        }
        xin[gid] = v;
    }
}

__global__ void __launch_bounds__(TPB, 2) lstm_kernel(
    const float* __restrict__ xin,
    const float* __restrict__ hid0, const float* __restrict__ cel0,
    const float* __restrict__ Wih0, const float* __restrict__ Whh0,
    const float* __restrict__ bih0, const float* __restrict__ bhh0,
    const float* __restrict__ Wih1, const float* __restrict__ Whh1,
    const float* __restrict__ bih1, const float* __restrict__ bhh1,
    float* __restrict__ out,
    unsigned long long* __restrict__ h0pkt,   // [4096][512] : tag|h0 pair
    unsigned long long* __restrict__ h1pkt)   // [4096][512] : tag|h1 pair
{
    __shared__ unsigned hs2[1024];            // half2 chunks of the input vector(s)
    __shared__ unsigned long long stg[16];    // per-block outgoing packet staging
    const int tid  = threadIdx.x;
    const int lane = tid & 63;
    const int wave = tid >> 6;
    const int bx   = blockIdx.x;

    if (bx < 32) {
        // ================= layer 0 : 32 blocks, wave owns 4 h-indices ========
        const int j0 = bx * 32 + wave * 4;
        unsigned w2[4][4][8];     // f16-pair weights of Whh0
        float    wx[4][4];        // fp32 x-weights (lane < 33)
        float    bs[4][4];
#pragma unroll
        for (int jj = 0; jj < 4; ++jj) {
#pragma unroll
            for (int g = 0; g < 4; ++g) {
                const int row = g * Hn + (j0 + jj);
                const float* wr = Whh0 + (size_t)row * Hn;
#pragma unroll
                for (int k = 0; k < 8; ++k) {
                    int c = lane + 64 * k;
                    w2[jj][g][k] = pack2(wr[2 * c], wr[2 * c + 1]);
                }
                wx[jj][g] = (lane < INW) ? Wih0[row * INW + lane] : 0.0f;
                bs[jj][g] = bih0[row] + bhh0[row];
            }
        }
        float cst[4], hcur[4];
#pragma unroll
        for (int jj = 0; jj < 4; ++jj) { cst[jj] = cel0[j0 + jj]; hcur[jj] = 0.0f; }

        for (int t = 0; t < Bn; ++t) {
            float xv = xin[t * INW + (lane < INW ? lane : 0)];  // prefetch (L2-hot)
            if (wave == 0) {
                if (t == 0) {
#pragma unroll
                    for (int m = 0; m < 8; ++m) {
                        int q = lane + 64 * m;
                        hs2[q] = pack2(hid0[2 * q], hid0[2 * q + 1]);
                    }
                } else {
                    uint4v r0, r1, r2, r3;
                    poll_row(h0pkt + (size_t)(t - 1) * 512, lane, (unsigned)t, r0, r1, r2, r3);
                    row_to_lds(hs2, 0, lane, r0, r1, r2, r3);
                }
            }
            __syncthreads();                  // barrier A: hs2 ready

            float acc[4][4];
#pragma unroll
            for (int jj = 0; jj < 4; ++jj)
#pragma unroll
                for (int g = 0; g < 4; ++g) acc[jj][g] = wx[jj][g] * xv;
#pragma unroll
            for (int k = 0; k < 8; ++k) {
                unsigned hv = hs2[lane + 64 * k];   // 2-way bank alias: free
#pragma unroll
                for (int jj = 0; jj < 4; ++jj)
#pragma unroll
                    for (int g = 0; g < 4; ++g)
                        acc[jj][g] = dot2acc(w2[jj][g][k], hv, acc[jj][g]);
            }
            __syncthreads();                  // barrier B: hs2 reads done

#pragma unroll
            for (int off = 32; off >= 1; off >>= 1)
#pragma unroll
                for (int jj = 0; jj < 4; ++jj)
#pragma unroll
                    for (int g = 0; g < 4; ++g)
                        acc[jj][g] += __shfl_xor(acc[jj][g], off);

#pragma unroll
            for (int jj = 0; jj < 4; ++jj) {
                float gi = sigmoidf_(acc[jj][0] + bs[jj][0]);
                float gf = sigmoidf_(acc[jj][1] + bs[jj][1]);
                float gg = tanhf_   (acc[jj][2] + bs[jj][2]);
                float go = sigmoidf_(acc[jj][3] + bs[jj][3]);
                cst[jj] = gf * cst[jj] + gi * gg;
                hcur[jj] = go * tanhf_(cst[jj]);
            }
            // stage this wave's 2 packets in LDS; one wave bursts the whole
            // 128 B block segment (writer-starvation fix: 1 coalesced write
            // transaction per line instead of 4 scattered 8 B stores).
            if (lane == 0) {
                unsigned long long tw = ((unsigned long long)(t + 1)) << 32;
                stg[2 * wave]     = tw | pack2(hcur[0], hcur[1]);
                stg[2 * wave + 1] = tw | pack2(hcur[2], hcur[3]);
            }
            __syncthreads();                  // barrier C: stg ready
            if (wave == 0 && lane < 8) {
                uint4v v = *(const uint4v*)&stg[2 * lane];
                char* dst = (char*)(h0pkt + (size_t)t * 512) + bx * 128 + lane * 16;
                store16_coherent(dst, v);
            }
        }
        if (lane == 0) {
#pragma unroll
            for (int jj = 0; jj < 4; ++jj) {
                out[OUTS + j0 + jj] = hcur[jj];            // hf layer 0
                out[OUTS + 2 * Hn + j0 + jj] = cst[jj];    // cf layer 0
            }
        }
    } else {
        // ================= layer 1 : 64 blocks, wave owns 2 h-indices ========
        const int blk = bx - 32;
        const int j0  = blk * 16 + wave * 2;
        unsigned w2[2][4][16];    // k<8: Wih1 (vs h0[t]) ; k>=8: Whh1 (vs h1[t-1])
        float    bs[2][4];
#pragma unroll
        for (int jj = 0; jj < 2; ++jj) {
#pragma unroll
            for (int g = 0; g < 4; ++g) {
                const int row = g * Hn + (j0 + jj);
                const float* wr1 = Wih1 + (size_t)row * Hn;
                const float* wr2 = Whh1 + (size_t)row * Hn;
#pragma unroll
                for (int k = 0; k < 8; ++k) {
                    int c = lane + 64 * k;
                    w2[jj][g][k]     = pack2(wr1[2 * c], wr1[2 * c + 1]);
                    w2[jj][g][8 + k] = pack2(wr2[2 * c], wr2[2 * c + 1]);
                }
                bs[jj][g] = bih1[row] + bhh1[row];
            }
        }
        float cst[2], hcur[2];
#pragma unroll
        for (int jj = 0; jj < 2; ++jj) { cst[jj] = cel0[Hn + j0 + jj]; hcur[jj] = 0.0f; }

        for (int t = 0; t < Bn; ++t) {
            if (wave == 0) {
                uint4v r0, r1, r2, r3;
                poll_row(h0pkt + (size_t)t * 512, lane, (unsigned)(t + 1), r0, r1, r2, r3);
                row_to_lds(hs2, 0, lane, r0, r1, r2, r3);          // h0[t]
            } else if (wave == 1) {
                if (t == 0) {
#pragma unroll
                    for (int m = 0; m < 8; ++m) {
                        int q = lane + 64 * m;
                        hs2[512 + q] = pack2(hid0[Hn + 2 * q], hid0[Hn + 2 * q + 1]);
                    }
                } else {
                    uint4v r0, r1, r2, r3;
                    poll_row(h1pkt + (size_t)(t - 1) * 512, lane, (unsigned)t, r0, r1, r2, r3);
                    row_to_lds(hs2, 512, lane, r0, r1, r2, r3);    // h1[t-1]
                }
            }
            __syncthreads();                  // barrier A

            float acc[2][4];
#pragma unroll
            for (int jj = 0; jj < 2; ++jj)
#pragma unroll
                for (int g = 0; g < 4; ++g) acc[jj][g] = 0.0f;
#pragma unroll
            for (int k = 0; k < 16; ++k) {
                unsigned hv = hs2[lane + 64 * k];
#pragma unroll
                for (int jj = 0; jj < 2; ++jj)
#pragma unroll
                    for (int g = 0; g < 4; ++g)
                        acc[jj][g] = dot2acc(w2[jj][g][k], hv, acc[jj][g]);
            }
            __syncthreads();                  // barrier B

#pragma unroll
            for (int off = 32; off >= 1; off >>= 1)
#pragma unroll
                for (int jj = 0; jj < 2; ++jj)
#pragma unroll
                    for (int g = 0; g < 4; ++g)
                        acc[jj][g] += __shfl_xor(acc[jj][g], off);

#pragma unroll
            for (int jj = 0; jj < 2; ++jj) {
                float gi = sigmoidf_(acc[jj][0] + bs[jj][0]);
                float gf = sigmoidf_(acc[jj][1] + bs[jj][1]);
                float gg = tanhf_   (acc[jj][2] + bs[jj][2]);
                float go = sigmoidf_(acc[jj][3] + bs[jj][3]);
                cst[jj] = gf * cst[jj] + gi * gg;
                hcur[jj] = go * tanhf_(cst[jj]);
            }
            if (lane == 0) {
                unsigned long long tw = ((unsigned long long)(t + 1)) << 32;
                stg[wave] = tw | pack2(hcur[0], hcur[1]);
                float2 o2 = make_float2(fmaxf(hcur[0], 0.0f), fmaxf(hcur[1], 0.0f));
                *(float2*)(out + (size_t)t * Hn + j0) = o2;   // outputs[t] = relu(h1)
            }
            __syncthreads();                  // barrier C: stg ready
            if (wave == 0 && lane < 4) {
                uint4v v = *(const uint4v*)&stg[2 * lane];
                char* dst = (char*)(h1pkt + (size_t)t * 512) + blk * 64 + lane * 16;
                store16_coherent(dst, v);
            }
        }
        if (lane == 0) {
#pragma unroll
            for (int jj = 0; jj < 2; ++jj) {
                out[OUTS + Hn + j0 + jj] = hcur[jj];           // hf layer 1
                out[OUTS + 3 * Hn + j0 + jj] = cst[jj];        // cf layer 1
            }
        }
    }
}

extern "C" void kernel_launch(void* const* d_in, const int* in_sizes, int n_in,
                              void* d_out, int out_size, void* d_ws, size_t ws_size,
                              hipStream_t stream) {
    const float* x        = (const float*)d_in[0];
    const int*   ip       = (const int*)d_in[1];
    const int*   port     = (const int*)d_in[2];
    const float* hidden   = (const float*)d_in[3];
    const float* cell     = (const float*)d_in[4];
    const float* ip_emb   = (const float*)d_in[5];
    const float* port_emb = (const float*)d_in[6];
    const float* Wih0     = (const float*)d_in[7];
    const float* Whh0     = (const float*)d_in[8];
    const float* bih0     = (const float*)d_in[9];
    const float* bhh0     = (const float*)d_in[10];
    const float* Wih1     = (const float*)d_in[11];
    const float* Whh1     = (const float*)d_in[12];
    const float* bih1     = (const float*)d_in[13];
    const float* bhh1     = (const float*)d_in[14];
    float* out = (float*)d_out;

    // ws layout: h0pkt (4096x512 u64) | h1pkt (4096x512 u64) | xin (4096x33 f32)
    // Tags are t+1 in the high 32 bits; the 0xAA poison never matches, so no
    // zeroing pass is needed.
    unsigned long long* h0pkt = (unsigned long long*)d_ws;
    unsigned long long* h1pkt = h0pkt + (size_t)Bn * 512;
    float* xin = (float*)(h1pkt + (size_t)Bn * 512);

    prep_kernel<<<dim3((Bn * INW + 255) / 256), dim3(256), 0, stream>>>(
        x, ip, port, ip_emb, port_emb, xin);

    lstm_kernel<<<dim3(96), dim3(TPB), 0, stream>>>(
        xin, hidden, cell, Wih0, Whh0, bih0, bhh0, Wih1, Whh1, bih1, bhh1,
        out, h0pkt, h1pkt);
}

// Round 6
// 17288.013 us; speedup vs baseline: 2.2408x; 1.0215x over previous
//
#include <hip/hip_runtime.h>
#include <hip/hip_fp16.h>
#include <math.h>

#define Hn 1024
#define Bn 4096
#define INW 33
#define OUTS (Bn * Hn)
#define TPB 512

typedef _Float16 half2v __attribute__((ext_vector_type(2)));
typedef unsigned uint4v __attribute__((ext_vector_type(4)));

__device__ __forceinline__ float sigmoidf_(float x) {
    return 1.0f / (1.0f + __expf(-x));
}
__device__ __forceinline__ float tanhf_(float x) {
    float e = __expf(-2.0f * fabsf(x));
    float r = (1.0f - e) / (1.0f + e);
    return copysignf(r, x);
}
__device__ __forceinline__ unsigned pack2(float a, float b) {
    __half2 h = __floats2half2_rn(a, b);
    return __builtin_bit_cast(unsigned, h);
}
__device__ __forceinline__ float dot2acc(unsigned w, unsigned hv, float acc) {
#if __has_builtin(__builtin_amdgcn_fdot2)
    return __builtin_amdgcn_fdot2(__builtin_bit_cast(half2v, w),
                                  __builtin_bit_cast(half2v, hv), acc, false);
#else
    __half2 wh = __builtin_bit_cast(__half2, w);
    __half2 hh = __builtin_bit_cast(__half2, hv);
    float2 wf = __half22float2(wh), hf = __half22float2(hh);
    return acc + wf.x * hf.x + wf.y * hf.y;
#endif
}

// Cheap detection spin: ALL 64 lanes load the SAME 8 B packet (wave-uniform
// address -> 1 coherent line-request per round, vs 64 for a full-row spin).
// Probe packet is hashed per consumer so different waves watch different
// single-writer lines (R4 lesson: many *writers* per line is fatal; many
// readers on one single-writer line is the safe direction, and we spread
// readers anyway).
__device__ __forceinline__ void probe_spin(const unsigned long long* p, unsigned tag) {
    int rounds = 0;
    for (;;) {
        unsigned long long v;
        asm volatile("global_load_dwordx2 %0, %1, off sc0 sc1\n\t"
                     "s_waitcnt vmcnt(0)"
                     : "=v"(v) : "v"(p) : "memory");
        if ((unsigned)(v >> 32) == tag) break;
        if (++rounds > (1 << 24)) break;   // bailout: wrong answer beats a wedged GPU
        if (rounds > 4) __builtin_amdgcn_s_sleep(1);
    }
}

// Tag-verified full-row read (4 KB, data-is-the-flag). After probe_spin this
// usually completes in 1-2 rounds (producers are in lockstep; only stragglers
// force a retry). Lane i owns 16 B at row + 16*i per 1 KB stripe.
__device__ __forceinline__ void poll_row(const unsigned long long* rowbase, int lane,
                                         unsigned tag, uint4v& r0, uint4v& r1,
                                         uint4v& r2, uint4v& r3) {
    const char* p = (const char*)rowbase + lane * 16;
    int rounds = 0;
    for (;;) {
        asm volatile(
            "global_load_dwordx4 %0, %4, off sc0 sc1\n\t"
            "global_load_dwordx4 %1, %4, off offset:1024 sc0 sc1\n\t"
            "global_load_dwordx4 %2, %4, off offset:2048 sc0 sc1\n\t"
            "global_load_dwordx4 %3, %4, off offset:3072 sc0 sc1\n\t"
            "s_waitcnt vmcnt(0)"
            : "=v"(r0), "=v"(r1), "=v"(r2), "=v"(r3)
            : "v"(p)
            : "memory");
        bool ok = (r0.y == tag) & (r0.w == tag) & (r1.y == tag) & (r1.w == tag)
                & (r2.y == tag) & (r2.w == tag) & (r3.y == tag) & (r3.w == tag);
        if (__all(ok)) break;
        if (++rounds > (1 << 22)) break;  // bailout
        if (rounds > 2) __builtin_amdgcn_s_sleep(1);
    }
}

// deposit a polled row into LDS at hs2[base .. base+511]
__device__ __forceinline__ void row_to_lds(unsigned* hs2, int base, int lane,
                                           const uint4v& r0, const uint4v& r1,
                                           const uint4v& r2, const uint4v& r3) {
    hs2[base +       2 * lane]     = r0.x;  hs2[base +       2 * lane + 1] = r0.z;
    hs2[base + 128 + 2 * lane]     = r1.x;  hs2[base + 128 + 2 * lane + 1] = r1.z;
    hs2[base + 256 + 2 * lane]     = r2.x;  hs2[base + 256 + 2 * lane + 1] = r2.z;
    hs2[base + 384 + 2 * lane]     = r3.x;  hs2[base + 384 + 2 * lane + 1] = r3.z;
}

__device__ __forceinline__ void store16_coherent(void* dst, uint4v v) {
    asm volatile("global_store_dwordx4 %0, %1, off sc0 sc1"
                 :: "v"(dst), "v"(v) : "memory");
}

// xin = [x | ip_emb[ip] | port_emb[port]]  (4096 x 33)
__global__ void prep_kernel(const float* __restrict__ x, const int* __restrict__ ip,
                            const int* __restrict__ port, const float* __restrict__ ip_emb,
                            const float* __restrict__ port_emb, float* __restrict__ xin) {
    int gid = blockIdx.x * blockDim.x + threadIdx.x;
    if (gid < Bn * INW) {
        int t = gid / INW;
        int k = gid - t * INW;
        float v;
        if (k < 17) {
            v = x[t * 17 + k];
        } else if (k < 25) {
            v = ip_emb[ip[t * 8 + (k - 17)]];
        } else {
            int kk = k - 25;
            v = port_emb[port[t * 2 + (kk >> 2)] * 4 + (kk & 3)];
        }
        xin[gid] = v;
    }
}

__global__ void __launch_bounds__(TPB, 2) lstm_kernel(
    const float* __restrict__ xin,
    const float* __restrict__ hid0, const float* __restrict__ cel0,
    const float* __restrict__ Wih0, const float* __restrict__ Whh0,
    const float* __restrict__ bih0, const float* __restrict__ bhh0,
    const float* __restrict__ Wih1, const float* __restrict__ Whh1,
    const float* __restrict__ bih1, const float* __restrict__ bhh1,
    float* __restrict__ out,
    unsigned long long* __restrict__ h0pkt,   // [4096][512] : tag|h0 pair
    unsigned long long* __restrict__ h1pkt)   // [4096][512] : tag|h1 pair
{
    __shared__ unsigned hs2[1024];            // half2 chunks of the input vector(s)
    __shared__ unsigned long long stg[16];    // per-block outgoing packet staging
    const int tid  = threadIdx.x;
    const int lane = tid & 63;
    const int wave = tid >> 6;
    const int bx   = blockIdx.x;

    if (bx < 32) {
        // ================= layer 0 : 32 blocks, wave owns 4 h-indices ========
        const int j0 = bx * 32 + wave * 4;
        const int probe0 = (bx * 67 + 13) & 511;     // this consumer's probe packet
        unsigned w2[4][4][8];     // f16-pair weights of Whh0
        float    wx[4][4];        // fp32 x-weights (lane < 33)
        float    bs[4][4];
#pragma unroll
        for (int jj = 0; jj < 4; ++jj) {
#pragma unroll
            for (int g = 0; g < 4; ++g) {
                const int row = g * Hn + (j0 + jj);
                const float* wr = Whh0 + (size_t)row * Hn;
#pragma unroll
                for (int k = 0; k < 8; ++k) {
                    int c = lane + 64 * k;
                    w2[jj][g][k] = pack2(wr[2 * c], wr[2 * c + 1]);
                }
                wx[jj][g] = (lane < INW) ? Wih0[row * INW + lane] : 0.0f;
                bs[jj][g] = bih0[row] + bhh0[row];
            }
        }
        float cst[4], hcur[4];
#pragma unroll
        for (int jj = 0; jj < 4; ++jj) { cst[jj] = cel0[j0 + jj]; hcur[jj] = 0.0f; }

        for (int t = 0; t < Bn; ++t) {
            float xv = xin[t * INW + (lane < INW ? lane : 0)];  // prefetch (L2-hot)
            if (wave == 0) {
                if (t == 0) {
#pragma unroll
                    for (int m = 0; m < 8; ++m) {
                        int q = lane + 64 * m;
                        hs2[q] = pack2(hid0[2 * q], hid0[2 * q + 1]);
                    }
                } else {
                    const unsigned long long* rb = h0pkt + (size_t)(t - 1) * 512;
                    probe_spin(rb + probe0, (unsigned)t);
                    uint4v r0, r1, r2, r3;
                    poll_row(rb, lane, (unsigned)t, r0, r1, r2, r3);
                    row_to_lds(hs2, 0, lane, r0, r1, r2, r3);
                }
            }
            __syncthreads();                  // barrier A: hs2 ready

            float acc[4][4];
#pragma unroll
            for (int jj = 0; jj < 4; ++jj)
#pragma unroll
                for (int g = 0; g < 4; ++g) acc[jj][g] = wx[jj][g] * xv;
#pragma unroll
            for (int k = 0; k < 8; ++k) {
                unsigned hv = hs2[lane + 64 * k];   // 2-way bank alias: free
#pragma unroll
                for (int jj = 0; jj < 4; ++jj)
#pragma unroll
                    for (int g = 0; g < 4; ++g)
                        acc[jj][g] = dot2acc(w2[jj][g][k], hv, acc[jj][g]);
            }
            __syncthreads();                  // barrier B: hs2 reads done

#pragma unroll
            for (int off = 32; off >= 1; off >>= 1)
#pragma unroll
                for (int jj = 0; jj < 4; ++jj)
#pragma unroll
                    for (int g = 0; g < 4; ++g)
                        acc[jj][g] += __shfl_xor(acc[jj][g], off);

#pragma unroll
            for (int jj = 0; jj < 4; ++jj) {
                float gi = sigmoidf_(acc[jj][0] + bs[jj][0]);
                float gf = sigmoidf_(acc[jj][1] + bs[jj][1]);
                float gg = tanhf_   (acc[jj][2] + bs[jj][2]);
                float go = sigmoidf_(acc[jj][3] + bs[jj][3]);
                cst[jj] = gf * cst[jj] + gi * gg;
                hcur[jj] = go * tanhf_(cst[jj]);
            }
            // stage this wave's 2 packets in LDS; wave 0 bursts the whole
            // 128 B block segment (single coalesced write per line).
            if (lane == 0) {
                unsigned long long tw = ((unsigned long long)(t + 1)) << 32;
                stg[2 * wave]     = tw | pack2(hcur[0], hcur[1]);
                stg[2 * wave + 1] = tw | pack2(hcur[2], hcur[3]);
            }
            __syncthreads();                  // barrier C: stg ready
            if (wave == 0 && lane < 8) {
                uint4v v = *(const uint4v*)&stg[2 * lane];
                char* dst = (char*)(h0pkt + (size_t)t * 512) + bx * 128 + lane * 16;
                store16_coherent(dst, v);
            }
        }
        if (lane == 0) {
#pragma unroll
            for (int jj = 0; jj < 4; ++jj) {
                out[OUTS + j0 + jj] = hcur[jj];            // hf layer 0
                out[OUTS + 2 * Hn + j0 + jj] = cst[jj];    // cf layer 0
            }
        }
    } else {
        // ================= layer 1 : 64 blocks, wave owns 2 h-indices ========
        const int blk = bx - 32;
        const int j0  = blk * 16 + wave * 2;
        const int probeA = ((blk + 64) * 67 + 13) & 511;  // h0-row probe
        const int probeB = (blk * 67 + 13) & 511;         // h1-row probe
        unsigned w2[2][4][16];    // k<8: Wih1 (vs h0[t]) ; k>=8: Whh1 (vs h1[t-1])
        float    bs[2][4];
#pragma unroll
        for (int jj = 0; jj < 2; ++jj) {
#pragma unroll
            for (int g = 0; g < 4; ++g) {
                const int row = g * Hn + (j0 + jj);
                const float* wr1 = Wih1 + (size_t)row * Hn;
                const float* wr2 = Whh1 + (size_t)row * Hn;
#pragma unroll
                for (int k = 0; k < 8; ++k) {
                    int c = lane + 64 * k;
                    w2[jj][g][k]     = pack2(wr1[2 * c], wr1[2 * c + 1]);
                    w2[jj][g][8 + k] = pack2(wr2[2 * c], wr2[2 * c + 1]);
                }
                bs[jj][g] = bih1[row] + bhh1[row];
            }
        }
        float cst[2], hcur[2];
#pragma unroll
        for (int jj = 0; jj < 2; ++jj) { cst[jj] = cel0[Hn + j0 + jj]; hcur[jj] = 0.0f; }

        for (int t = 0; t < Bn; ++t) {
            if (wave == 0) {
                const unsigned long long* rb = h0pkt + (size_t)t * 512;
                probe_spin(rb + probeA, (unsigned)(t + 1));
                uint4v r0, r1, r2, r3;
                poll_row(rb, lane, (unsigned)(t + 1), r0, r1, r2, r3);
                row_to_lds(hs2, 0, lane, r0, r1, r2, r3);          // h0[t]
            } else if (wave == 1) {
                if (t == 0) {
#pragma unroll
                    for (int m = 0; m < 8; ++m) {
                        int q = lane + 64 * m;
                        hs2[512 + q] = pack2(hid0[Hn + 2 * q], hid0[Hn + 2 * q + 1]);
                    }
                } else {
                    const unsigned long long* rb = h1pkt + (size_t)(t - 1) * 512;
                    probe_spin(rb + probeB, (unsigned)t);
                    uint4v r0, r1, r2, r3;
                    poll_row(rb, lane, (unsigned)t, r0, r1, r2, r3);
                    row_to_lds(hs2, 512, lane, r0, r1, r2, r3);    // h1[t-1]
                }
            }
            __syncthreads();                  // barrier A

            float acc[2][4];
#pragma unroll
            for (int jj = 0; jj < 2; ++jj)
#pragma unroll
                for (int g = 0; g < 4; ++g) acc[jj][g] = 0.0f;
#pragma unroll
            for (int k = 0; k < 16; ++k) {
                unsigned hv = hs2[lane + 64 * k];
#pragma unroll
                for (int jj = 0; jj < 2; ++jj)
#pragma unroll
                    for (int g = 0; g < 4; ++g)
                        acc[jj][g] = dot2acc(w2[jj][g][k], hv, acc[jj][g]);
            }
            __syncthreads();                  // barrier B

#pragma unroll
            for (int off = 32; off >= 1; off >>= 1)
#pragma unroll
                for (int jj = 0; jj < 2; ++jj)
#pragma unroll
                    for (int g = 0; g < 4; ++g)
                        acc[jj][g] += __shfl_xor(acc[jj][g], off);

#pragma unroll
            for (int jj = 0; jj < 2; ++jj) {
                float gi = sigmoidf_(acc[jj][0] + bs[jj][0]);
                float gf = sigmoidf_(acc[jj][1] + bs[jj][1]);
                float gg = tanhf_   (acc[jj][2] + bs[jj][2]);
                float go = sigmoidf_(acc[jj][3] + bs[jj][3]);
                cst[jj] = gf * cst[jj] + gi * gg;
                hcur[jj] = go * tanhf_(cst[jj]);
            }
            if (lane == 0) {
                unsigned long long tw = ((unsigned long long)(t + 1)) << 32;
                stg[wave] = tw | pack2(hcur[0], hcur[1]);
                float2 o2 = make_float2(fmaxf(hcur[0], 0.0f), fmaxf(hcur[1], 0.0f));
                *(float2*)(out + (size_t)t * Hn + j0) = o2;   // outputs[t] = relu(h1)
            }
            __syncthreads();                  // barrier C: stg ready
            if (wave == 0 && lane < 4) {
                uint4v v = *(const uint4v*)&stg[2 * lane];
                char* dst = (char*)(h1pkt + (size_t)t * 512) + blk * 64 + lane * 16;
                store16_coherent(dst, v);
            }
        }
        if (lane == 0) {
#pragma unroll
            for (int jj = 0; jj < 2; ++jj) {
                out[OUTS + Hn + j0 + jj] = hcur[jj];           // hf layer 1
                out[OUTS + 3 * Hn + j0 + jj] = cst[jj];        // cf layer 1
            }
        }
    }
}

extern "C" void kernel_launch(void* const* d_in, const int* in_sizes, int n_in,
                              void* d_out, int out_size, void* d_ws, size_t ws_size,
                              hipStream_t stream) {
    const float* x        = (const float*)d_in[0];
    const int*   ip       = (const int*)d_in[1];
    const int*   port     = (const int*)d_in[2];
    const float* hidden   = (const float*)d_in[3];
    const float* cell     = (const float*)d_in[4];
    const float* ip_emb   = (const float*)d_in[5];
    const float* port_emb = (const float*)d_in[6];
    const float* Wih0     = (const float*)d_in[7];
    const float* Whh0     = (const float*)d_in[8];
    const float* bih0     = (const float*)d_in[9];
    const float* bhh0     = (const float*)d_in[10];
    const float* Wih1     = (const float*)d_in[11];
    const float* Whh1     = (const float*)d_in[12];
    const float* bih1     = (const float*)d_in[13];
    const float* bhh1     = (const float*)d_in[14];
    float* out = (float*)d_out;

    // ws layout: h0pkt (4096x512 u64) | h1pkt (4096x512 u64) | xin (4096x33 f32)
    // Tags are t+1 in the high 32 bits; the 0xAA poison never matches, so no
    // zeroing pass is needed.
    unsigned long long* h0pkt = (unsigned long long*)d_ws;
    unsigned long long* h1pkt = h0pkt + (size_t)Bn * 512;
    float* xin = (float*)(h1pkt + (size_t)Bn * 512);

    prep_kernel<<<dim3((Bn * INW + 255) / 256), dim3(256), 0, stream>>>(
        x, ip, port, ip_emb, port_emb, xin);

    lstm_kernel<<<dim3(96), dim3(TPB), 0, stream>>>(
        xin, hidden, cell, Wih0, Whh0, bih0, bhh0, Wih1, Whh1, bih1, bhh1,
        out, h0pkt, h1pkt);
}

// Round 7
// 17225.192 us; speedup vs baseline: 2.2489x; 1.0036x over previous
//
#include <hip/hip_runtime.h>
#include <hip/hip_fp16.h>
#include <math.h>

#define Hn 1024
#define Bn 4096
#define INW 33
#define OUTS (Bn * Hn)
#define TPB 512
#define ROWP 1024   // packets per exchange row: [h0 half | h1 half]

typedef _Float16 half2v __attribute__((ext_vector_type(2)));
typedef unsigned uint4v __attribute__((ext_vector_type(4)));

__device__ __forceinline__ float sigmoidf_(float x) {
    return 1.0f / (1.0f + __expf(-x));
}
__device__ __forceinline__ float tanhf_(float x) {
    float e = __expf(-2.0f * fabsf(x));
    float r = (1.0f - e) / (1.0f + e);
    return copysignf(r, x);
}
__device__ __forceinline__ unsigned pack2(float a, float b) {
    __half2 h = __floats2half2_rn(a, b);
    return __builtin_bit_cast(unsigned, h);
}
__device__ __forceinline__ float dot2acc(unsigned w, unsigned hv, float acc) {
#if __has_builtin(__builtin_amdgcn_fdot2)
    return __builtin_amdgcn_fdot2(__builtin_bit_cast(half2v, w),
                                  __builtin_bit_cast(half2v, hv), acc, false);
#else
    __half2 wh = __builtin_bit_cast(__half2, w);
    __half2 hh = __builtin_bit_cast(__half2, hv);
    float2 wf = __half22float2(wh), hf = __half22float2(hh);
    return acc + wf.x * hf.x + wf.y * hf.y;
#endif
}

// Detection spin: all 64 lanes load the SAME 8 B packet (1 coherent
// line-request per round). Hard spin — no s_sleep (R5/R6 showed sleep-based
// backoff is bistable: occasional 47 ms slow-mode dispatches).
__device__ __forceinline__ void probe_spin(const unsigned long long* p, unsigned tag) {
    int rounds = 0;
    for (;;) {
        unsigned long long v;
        asm volatile("global_load_dwordx2 %0, %1, off sc0 sc1\n\t"
                     "s_waitcnt vmcnt(0)"
                     : "=v"(v) : "v"(p) : "memory");
        if ((unsigned)(v >> 32) == tag) break;
        if (++rounds > (1 << 24)) break;   // bailout: wrong answer beats a wedged GPU
    }
}

// Tag-verified 512-packet (4 KB) half-row read, data-is-the-flag.
// Lane i owns 16 B at base + 16*i per 1 KB stripe.
__device__ __forceinline__ void poll_row(const unsigned long long* halfbase, int lane,
                                         unsigned tag, uint4v& r0, uint4v& r1,
                                         uint4v& r2, uint4v& r3) {
    const char* p = (const char*)halfbase + lane * 16;
    int rounds = 0;
    for (;;) {
        asm volatile(
            "global_load_dwordx4 %0, %4, off sc0 sc1\n\t"
            "global_load_dwordx4 %1, %4, off offset:1024 sc0 sc1\n\t"
            "global_load_dwordx4 %2, %4, off offset:2048 sc0 sc1\n\t"
            "global_load_dwordx4 %3, %4, off offset:3072 sc0 sc1\n\t"
            "s_waitcnt vmcnt(0)"
            : "=v"(r0), "=v"(r1), "=v"(r2), "=v"(r3)
            : "v"(p)
            : "memory");
        bool ok = (r0.y == tag) & (r0.w == tag) & (r1.y == tag) & (r1.w == tag)
                & (r2.y == tag) & (r2.w == tag) & (r3.y == tag) & (r3.w == tag);
        if (__all(ok)) break;
        if (++rounds > (1 << 22)) break;  // bailout
    }
}

// deposit a polled half-row into LDS at hs2[base .. base+511]
__device__ __forceinline__ void row_to_lds(unsigned* hs2, int base, int lane,
                                           const uint4v& r0, const uint4v& r1,
                                           const uint4v& r2, const uint4v& r3) {
    hs2[base +       2 * lane]     = r0.x;  hs2[base +       2 * lane + 1] = r0.z;
    hs2[base + 128 + 2 * lane]     = r1.x;  hs2[base + 128 + 2 * lane + 1] = r1.z;
    hs2[base + 256 + 2 * lane]     = r2.x;  hs2[base + 256 + 2 * lane + 1] = r2.z;
    hs2[base + 384 + 2 * lane]     = r3.x;  hs2[base + 384 + 2 * lane + 1] = r3.z;
}

__device__ __forceinline__ void store16_coherent(void* dst, uint4v v) {
    asm volatile("global_store_dwordx4 %0, %1, off sc0 sc1"
                 :: "v"(dst), "v"(v) : "memory");
}

// xin = [x | ip_emb[ip] | port_emb[port]]  (4096 x 33)
__global__ void prep_kernel(const float* __restrict__ x, const int* __restrict__ ip,
                            const int* __restrict__ port, const float* __restrict__ ip_emb,
                            const float* __restrict__ port_emb, float* __restrict__ xin) {
    int gid = blockIdx.x * blockDim.x + threadIdx.x;
    if (gid < Bn * INW) {
        int t = gid / INW;
        int k = gid - t * INW;
        float v;
        if (k < 17) {
            v = x[t * 17 + k];
        } else if (k < 25) {
            v = ip_emb[ip[t * 8 + (k - 17)]];
        } else {
            int kk = k - 25;
            v = port_emb[port[t * 2 + (kk >> 2)] * 4 + (kk & 3)];
        }
        xin[gid] = v;
    }
}

// Skewed-superstep protocol. Row s (s = 0..Bn) holds [h0[s] | h1[s-1]],
// all packets tagged s+1. At superstep s, L0 blocks compute LSTM step s
// (consuming row s-1's h0 half), L1 blocks compute LSTM step s-1 (consuming
// BOTH halves of row s-1 — one tag phase, no intra-step L0->L1 serial leg).
__global__ void __launch_bounds__(TPB, 2) lstm_kernel(
    const float* __restrict__ xin,
    const float* __restrict__ hid0, const float* __restrict__ cel0,
    const float* __restrict__ Wih0, const float* __restrict__ Whh0,
    const float* __restrict__ bih0, const float* __restrict__ bhh0,
    const float* __restrict__ Wih1, const float* __restrict__ Whh1,
    const float* __restrict__ bih1, const float* __restrict__ bhh1,
    float* __restrict__ out,
    unsigned long long* __restrict__ rowpkt)  // [Bn+1][ROWP]
{
    __shared__ unsigned hs2[1024];            // half2 chunks of h0 / h0|h1
    __shared__ unsigned long long stg[16];    // per-block outgoing packet staging
    const int tid  = threadIdx.x;
    const int lane = tid & 63;
    const int wave = tid >> 6;
    const int bx   = blockIdx.x;

    if (bx < 32) {
        // ========== layer 0 : 32 blocks, wave owns 4 h-indices ==========
        const int j0 = bx * 32 + wave * 4;
        const int probe0 = (bx * 67 + 13) & 511;     // probe packet in h0 half
        unsigned w2[4][4][8];     // f16-pair weights of Whh0
        float    wx[4][4];        // fp32 x-weights (lane < 33)
        float    bs[4][4];
#pragma unroll
        for (int jj = 0; jj < 4; ++jj) {
#pragma unroll
            for (int g = 0; g < 4; ++g) {
                const int row = g * Hn + (j0 + jj);
                const float* wr = Whh0 + (size_t)row * Hn;
#pragma unroll
                for (int k = 0; k < 8; ++k) {
                    int c = lane + 64 * k;
                    w2[jj][g][k] = pack2(wr[2 * c], wr[2 * c + 1]);
                }
                wx[jj][g] = (lane < INW) ? Wih0[row * INW + lane] : 0.0f;
                bs[jj][g] = bih0[row] + bhh0[row];
            }
        }
        float cst[4], hcur[4];
#pragma unroll
        for (int jj = 0; jj < 4; ++jj) { cst[jj] = cel0[j0 + jj]; hcur[jj] = 0.0f; }

        for (int s = 0; s < Bn; ++s) {
            float xv = xin[s * INW + (lane < INW ? lane : 0)];  // prefetch (L2-hot)
            if (wave == 0) {
                if (s == 0) {
#pragma unroll
                    for (int m = 0; m < 8; ++m) {
                        int q = lane + 64 * m;
                        hs2[q] = pack2(hid0[2 * q], hid0[2 * q + 1]);
                    }
                } else {
                    const unsigned long long* rb = rowpkt + (size_t)(s - 1) * ROWP;
                    probe_spin(rb + probe0, (unsigned)s);
                    uint4v r0, r1, r2, r3;
                    poll_row(rb, lane, (unsigned)s, r0, r1, r2, r3);
                    row_to_lds(hs2, 0, lane, r0, r1, r2, r3);
                }
            }
            __syncthreads();                  // barrier A: hs2 ready

            float acc[4][4];
#pragma unroll
            for (int jj = 0; jj < 4; ++jj)
#pragma unroll
                for (int g = 0; g < 4; ++g) acc[jj][g] = wx[jj][g] * xv;
#pragma unroll
            for (int k = 0; k < 8; ++k) {
                unsigned hv = hs2[lane + 64 * k];   // 2-way bank alias: free
#pragma unroll
                for (int jj = 0; jj < 4; ++jj)
#pragma unroll
                    for (int g = 0; g < 4; ++g)
                        acc[jj][g] = dot2acc(w2[jj][g][k], hv, acc[jj][g]);
            }
            __syncthreads();                  // barrier B: hs2 reads done

#pragma unroll
            for (int off = 32; off >= 1; off >>= 1)
#pragma unroll
                for (int jj = 0; jj < 4; ++jj)
#pragma unroll
                    for (int g = 0; g < 4; ++g)
                        acc[jj][g] += __shfl_xor(acc[jj][g], off);

#pragma unroll
            for (int jj = 0; jj < 4; ++jj) {
                float gi = sigmoidf_(acc[jj][0] + bs[jj][0]);
                float gf = sigmoidf_(acc[jj][1] + bs[jj][1]);
                float gg = tanhf_   (acc[jj][2] + bs[jj][2]);
                float go = sigmoidf_(acc[jj][3] + bs[jj][3]);
                cst[jj] = gf * cst[jj] + gi * gg;
                hcur[jj] = go * tanhf_(cst[jj]);
            }
            // stage packets; wave 0 bursts the block's 128 B h0 segment
            if (lane == 0) {
                unsigned long long tw = ((unsigned long long)(s + 1)) << 32;
                stg[2 * wave]     = tw | pack2(hcur[0], hcur[1]);
                stg[2 * wave + 1] = tw | pack2(hcur[2], hcur[3]);
            }
            __syncthreads();                  // barrier C: stg ready
            if (wave == 0 && lane < 8) {
                uint4v v = *(const uint4v*)&stg[2 * lane];
                char* dst = (char*)(rowpkt + (size_t)s * ROWP) + bx * 128 + lane * 16;
                store16_coherent(dst, v);
            }
        }
        if (lane == 0) {
#pragma unroll
            for (int jj = 0; jj < 4; ++jj) {
                out[OUTS + j0 + jj] = hcur[jj];            // hf layer 0
                out[OUTS + 2 * Hn + j0 + jj] = cst[jj];    // cf layer 0
            }
        }
    } else {
        // ========== layer 1 : 64 blocks, wave owns 2 h-indices ==========
        const int blk = bx - 32;
        const int j0  = blk * 16 + wave * 2;
        const int probeA = ((blk + 64) * 67 + 13) & 511;         // h0-half probe
        const int probeB = 512 + ((blk * 67 + 13) & 511);        // h1-half probe
        unsigned w2[2][4][16];    // k<8: Wih1 (vs h0[s-1]) ; k>=8: Whh1 (vs h1[s-2])
        float    bs[2][4];
#pragma unroll
        for (int jj = 0; jj < 2; ++jj) {
#pragma unroll
            for (int g = 0; g < 4; ++g) {
                const int row = g * Hn + (j0 + jj);
                const float* wr1 = Wih1 + (size_t)row * Hn;
                const float* wr2 = Whh1 + (size_t)row * Hn;
#pragma unroll
                for (int k = 0; k < 8; ++k) {
                    int c = lane + 64 * k;
                    w2[jj][g][k]     = pack2(wr1[2 * c], wr1[2 * c + 1]);
                    w2[jj][g][8 + k] = pack2(wr2[2 * c], wr2[2 * c + 1]);
                }
                bs[jj][g] = bih1[row] + bhh1[row];
            }
        }
        float cst[2], hcur[2];
#pragma unroll
        for (int jj = 0; jj < 2; ++jj) { cst[jj] = cel0[Hn + j0 + jj]; hcur[jj] = 0.0f; }

        // superstep 0: publish initial h1 into row 0's h1 half (tag 1)
        if (lane == 0)
            stg[wave] = (1ULL << 32) | pack2(hid0[Hn + j0], hid0[Hn + j0 + 1]);
        __syncthreads();
        if (wave == 0 && lane < 4) {
            uint4v v = *(const uint4v*)&stg[2 * lane];
            char* dst = (char*)(rowpkt + 512) + blk * 64 + lane * 16;  // h1 half of row 0
            store16_coherent(dst, v);
        }

        for (int s = 1; s <= Bn; ++s) {
            const int t = s - 1;              // LSTM step this superstep computes
            const unsigned long long* rb = rowpkt + (size_t)(s - 1) * ROWP;
            if (wave == 0) {
                probe_spin(rb + probeA, (unsigned)s);
                uint4v r0, r1, r2, r3;
                poll_row(rb, lane, (unsigned)s, r0, r1, r2, r3);
                row_to_lds(hs2, 0, lane, r0, r1, r2, r3);          // h0[t]
            } else if (wave == 1) {
                probe_spin(rb + probeB, (unsigned)s);
                uint4v r0, r1, r2, r3;
                poll_row(rb + 512, lane, (unsigned)s, r0, r1, r2, r3);
                row_to_lds(hs2, 512, lane, r0, r1, r2, r3);        // h1[t-1]
            }
            __syncthreads();                  // barrier A

            float acc[2][4];
#pragma unroll
            for (int jj = 0; jj < 2; ++jj)
#pragma unroll
                for (int g = 0; g < 4; ++g) acc[jj][g] = 0.0f;
#pragma unroll
            for (int k = 0; k < 16; ++k) {
                unsigned hv = hs2[lane + 64 * k];
#pragma unroll
                for (int jj = 0; jj < 2; ++jj)
#pragma unroll
                    for (int g = 0; g < 4; ++g)
                        acc[jj][g] = dot2acc(w2[jj][g][k], hv, acc[jj][g]);
            }
            __syncthreads();                  // barrier B

#pragma unroll
            for (int off = 32; off >= 1; off >>= 1)
#pragma unroll
                for (int jj = 0; jj < 2; ++jj)
#pragma unroll
                    for (int g = 0; g < 4; ++g)
                        acc[jj][g] += __shfl_xor(acc[jj][g], off);

#pragma unroll
            for (int jj = 0; jj < 2; ++jj) {
                float gi = sigmoidf_(acc[jj][0] + bs[jj][0]);
                float gf = sigmoidf_(acc[jj][1] + bs[jj][1]);
                float gg = tanhf_   (acc[jj][2] + bs[jj][2]);
                float go = sigmoidf_(acc[jj][3] + bs[jj][3]);
                cst[jj] = gf * cst[jj] + gi * gg;
                hcur[jj] = go * tanhf_(cst[jj]);
            }
            if (lane == 0) {
                unsigned long long tw = ((unsigned long long)(s + 1)) << 32;
                stg[wave] = tw | pack2(hcur[0], hcur[1]);
                float2 o2 = make_float2(fmaxf(hcur[0], 0.0f), fmaxf(hcur[1], 0.0f));
                *(float2*)(out + (size_t)t * Hn + j0) = o2;   // outputs[t] = relu(h1)
            }
            __syncthreads();                  // barrier C: stg ready
            if (wave == 0 && lane < 4) {
                uint4v v = *(const uint4v*)&stg[2 * lane];
                char* dst = (char*)(rowpkt + (size_t)s * ROWP + 512) + blk * 64 + lane * 16;
                store16_coherent(dst, v);     // h1[t] into row s's h1 half
            }
        }
        if (lane == 0) {
#pragma unroll
            for (int jj = 0; jj < 2; ++jj) {
                out[OUTS + Hn + j0 + jj] = hcur[jj];           // hf layer 1
                out[OUTS + 3 * Hn + j0 + jj] = cst[jj];        // cf layer 1
            }
        }
    }
}

extern "C" void kernel_launch(void* const* d_in, const int* in_sizes, int n_in,
                              void* d_out, int out_size, void* d_ws, size_t ws_size,
                              hipStream_t stream) {
    const float* x        = (const float*)d_in[0];
    const int*   ip       = (const int*)d_in[1];
    const int*   port     = (const int*)d_in[2];
    const float* hidden   = (const float*)d_in[3];
    const float* cell     = (const float*)d_in[4];
    const float* ip_emb   = (const float*)d_in[5];
    const float* port_emb = (const float*)d_in[6];
    const float* Wih0     = (const float*)d_in[7];
    const float* Whh0     = (const float*)d_in[8];
    const float* bih0     = (const float*)d_in[9];
    const float* bhh0     = (const float*)d_in[10];
    const float* Wih1     = (const float*)d_in[11];
    const float* Whh1     = (const float*)d_in[12];
    const float* bih1     = (const float*)d_in[13];
    const float* bhh1     = (const float*)d_in[14];
    float* out = (float*)d_out;

    // ws layout: rowpkt ((Bn+1) x 1024 u64 = 33.6 MB) | xin (4096x33 f32).
    // Tags are s+1 in the high 32 bits; 0xAA poison never matches -> no
    // zeroing pass needed.
    unsigned long long* rowpkt = (unsigned long long*)d_ws;
    float* xin = (float*)(rowpkt + (size_t)(Bn + 1) * ROWP);

    prep_kernel<<<dim3((Bn * INW + 255) / 256), dim3(256), 0, stream>>>(
        x, ip, port, ip_emb, port_emb, xin);

    lstm_kernel<<<dim3(96), dim3(TPB), 0, stream>>>(
        xin, hidden, cell, Wih0, Whh0, bih0, bhh0, Wih1, Whh1, bih1, bhh1,
        out, rowpkt);
}